// Round 8
// baseline (7646.577 us; speedup 1.0000x reference)
//
#include <hip/hip_runtime.h>
#include <hip/hip_fp16.h>
#include <cstdint>

#define HH 128
#define GG 384   // 3H
#define TT 4000
#define BB 64

typedef uint32_t u32;

__device__ __forceinline__ float sigmf(float x) {
  return __fdividef(1.0f, 1.0f + __expf(-x));
}
__device__ __forceinline__ float tanh_fast(float x) {
  return __fdividef(2.0f, 1.0f + __expf(-2.0f * x)) - 1.0f;
}

template <int CTRL>
__device__ __forceinline__ float quad_add(float x) {
  int y = __builtin_amdgcn_mov_dpp(__float_as_int(x), CTRL, 0xF, 0xF, true);
  return x + __int_as_float(y);
}

// sum across the 8 lanes of a c-group (lane bits [2:0] = c):
// xor1 (quad_perm), xor2 (quad_perm), then row_half_mirror (0x141) crosses
// the 4-boundary within each 8-lane half-row.
__device__ __forceinline__ float reduce8(float x) {
  x = quad_add<0xB1>(x);
  x = quad_add<0x4E>(x);
  int y = __builtin_amdgcn_mov_dpp(__float_as_int(x), 0x141, 0xF, 0xF, true);
  return x + __int_as_float(y);
}

// v_dot2_f32_f16: d = a.x*b.x + a.y*b.y + c  (fp16 mul exact into fp32 acc)
__device__ __forceinline__ float fdot2(u32 a, u32 b, float c) {
  float d;
  asm("v_dot2_f32_f16 %0, %1, %2, %3" : "=v"(d) : "v"(a), "v"(b), "v"(c));
  return d;
}

__device__ __forceinline__ u32 packh2(float a, float b) {
  __half2 h = __floats2half2_rn(a, b);
  union { __half2 h; u32 u; } cv;
  cv.h = h;
  return cv.u;
}

// LDS-only barrier: do NOT drain vmcnt (keeps global prefetch/stores in flight).
__device__ __forceinline__ void wg_barrier_lds() {
  asm volatile("s_waitcnt lgkmcnt(0)" ::: "memory");
  __builtin_amdgcn_s_barrier();
  asm volatile("" ::: "memory");
}

// ---------------------------------------------------------------------------
// FUSED 2-layer GRU, 1024 threads = 128 q x 8 k-chunks = 16 waves (4/SIMD).
// Same as round 7 except the LDS h-write indexing bug is fixed:
// chunk stride is 12 u32 = 24 halves; round 7 wrote at u32 index (q>>4)*24
// (unit confusion, OOB for q>=64 -> stomped h2lds -> absmax 0.117).
// Correct: half index (q>>4)*24 + (q&15)  ==  u32 base (q>>4)*12.
// ---------------------------------------------------------------------------
__global__ __launch_bounds__(1024)
__attribute__((amdgpu_waves_per_eu(4, 4)))
void gru2_fused(
    const float* __restrict__ gx,     // [B,T,384] L0 input proj (incl bih0)
    const float* __restrict__ Whh0,   // [384,128]
    const float* __restrict__ bhh0,   // [384]
    const float* __restrict__ Wih1,   // [384,128]
    const float* __restrict__ bih1,   // [384]
    const float* __restrict__ Whh1,   // [384,128]
    const float* __restrict__ bhh1,   // [384]
    float* __restrict__ hout2,        // [B,T,ldh] L1 hidden states
    int ldh)
{
  // h as packed half2: 2 buffers x 8 chunks x (8 used + 4 pad) u32.
  // chunk stride 12 u32 = 48B: 16B-aligned for b128, bases spread over banks.
  __shared__ u32 h1lds[2][96];
  __shared__ u32 h2lds[2][96];

  const int tid = threadIdx.x;
  const int q = tid >> 3;   // 0..127
  const int c = tid & 7;    // k-chunk: k in [16c, 16c+16)
  const int b = blockIdx.x;
  const int rows[3] = { q, q + 128, q + 256 };

  // weights -> packed half2 registers (8 per row per matvec)
  u32 w0[3][8], wi[3][8], wh[3][8];
  #pragma unroll
  for (int rr = 0; rr < 3; ++rr) {
    const float4* p0 = reinterpret_cast<const float4*>(Whh0 + (size_t)rows[rr] * HH + c * 16);
    const float4* p1 = reinterpret_cast<const float4*>(Wih1 + (size_t)rows[rr] * HH + c * 16);
    const float4* p2 = reinterpret_cast<const float4*>(Whh1 + (size_t)rows[rr] * HH + c * 16);
    #pragma unroll
    for (int p = 0; p < 4; ++p) {
      float4 v0 = p0[p], v1 = p1[p], v2 = p2[p];
      w0[rr][p * 2 + 0] = packh2(v0.x, v0.y); w0[rr][p * 2 + 1] = packh2(v0.z, v0.w);
      wi[rr][p * 2 + 0] = packh2(v1.x, v1.y); wi[rr][p * 2 + 1] = packh2(v1.z, v1.w);
      wh[rr][p * 2 + 0] = packh2(v2.x, v2.y); wh[rr][p * 2 + 1] = packh2(v2.z, v2.w);
    }
  }
  #pragma unroll
  for (int rr = 0; rr < 3; ++rr)
    #pragma unroll
    for (int kk = 0; kk < 8; ++kk) {
      asm volatile("" : "+v"(w0[rr][kk]));
      asm volatile("" : "+v"(wi[rr][kk]));
      asm volatile("" : "+v"(wh[rr][kk]));
    }

  float bh0[3];
  #pragma unroll
  for (int rr = 0; rr < 3; ++rr) bh0[rr] = bhh0[rows[rr]];
  const float brz0 = bih1[rows[0]] + bhh1[rows[0]];
  const float brz1 = bih1[rows[1]] + bhh1[rows[1]];
  const float bin  = bih1[rows[2]];
  const float bhn  = bhh1[rows[2]];

  for (int i = tid; i < 192; i += 1024) {
    (&h1lds[0][0])[i] = 0u;
    (&h2lds[0][0])[i] = 0u;
  }

  const float* gxb = gx + (size_t)b * TT * GG;
  float* houtb = hout2 + (size_t)b * TT * ldh;

  float hprev1 = 0.0f, hprev2 = 0.0f;

  // gx prefetch, depth 2 (slot parity == step parity == LDS parity)
  float gxr[2][3];
  #pragma unroll
  for (int p = 0; p < 2; ++p) {
    const float* gxt = gxb + (size_t)p * GG;
    #pragma unroll
    for (int rr = 0; rr < 3; ++rr) gxr[p][rr] = gxt[rows[rr]];
  }

  __syncthreads();

  #pragma unroll 1
  for (int p2 = 0; p2 <= TT; p2 += 2) {
    #pragma unroll
    for (int s = 0; s < 2; ++s) {
      const int p = p2 + s;
      const int cur = s, nxt = s ^ 1;         // p2 even => p&1 == s
      const bool do0 = (p < TT);              // produce h1(p)
      const bool do1 = (p >= 1) && (p <= TT); // produce h2(p-1)

      // ---- read h1(p-1), h2(p-2) chunks: 2x b128 each ----
      u32 h1v[8], h2v[8];
      {
        const uint4* hp1 = reinterpret_cast<const uint4*>(&h1lds[cur][c * 12]);
        const uint4* hp2 = reinterpret_cast<const uint4*>(&h2lds[cur][c * 12]);
        uint4 x0 = hp1[0], x1 = hp1[1], y0 = hp2[0], y1 = hp2[1];
        h1v[0] = x0.x; h1v[1] = x0.y; h1v[2] = x0.z; h1v[3] = x0.w;
        h1v[4] = x1.x; h1v[5] = x1.y; h1v[6] = x1.z; h1v[7] = x1.w;
        h2v[0] = y0.x; h2v[1] = y0.y; h2v[2] = y0.z; h2v[3] = y0.w;
        h2v[4] = y1.x; h2v[5] = y1.y; h2v[6] = y1.z; h2v[7] = y1.w;
      }

      // ---- all dots, unconditional (edge steps read zero-init/dead data) ----
      float a0 = 0.f, a1 = 0.f, a2 = 0.f;
      float c_r = 0.f, c_z = 0.f, c_xn = 0.f, c_hn = 0.f;
      #pragma unroll
      for (int k2 = 0; k2 < 8; ++k2) {
        a0   = fdot2(h1v[k2], w0[0][k2], a0);
        a1   = fdot2(h1v[k2], w0[1][k2], a1);
        a2   = fdot2(h1v[k2], w0[2][k2], a2);
        c_r  = fdot2(h2v[k2], wh[0][k2], c_r);
        c_z  = fdot2(h2v[k2], wh[1][k2], c_z);
        c_hn = fdot2(h2v[k2], wh[2][k2], c_hn);
      }
      #pragma unroll
      for (int k2 = 0; k2 < 8; ++k2) {
        c_r  = fdot2(h1v[k2], wi[0][k2], c_r);
        c_z  = fdot2(h1v[k2], wi[1][k2], c_z);
        c_xn = fdot2(h1v[k2], wi[2][k2], c_xn);
      }

      // ---- reduce across the 8 c-lanes ----
      a0 = reduce8(a0); a1 = reduce8(a1); a2 = reduce8(a2);
      c_r = reduce8(c_r); c_z = reduce8(c_z);
      c_xn = reduce8(c_xn); c_hn = reduce8(c_hn);

      // ---- L0 gates ----
      if (do0) {
        const float r = sigmf(gxr[s][0] + a0 + bh0[0]);
        const float z = sigmf(gxr[s][1] + a1 + bh0[1]);
        const float n = tanh_fast(gxr[s][2] + r * (a2 + bh0[2]));
        const float h1n = (1.0f - z) * n + z * hprev1;
        hprev1 = h1n;
        if (c == 0) {
          // half index within padded layout: chunk (q>>4) has 24 halves
          __half* hw = reinterpret_cast<__half*>(&h1lds[nxt][0]);
          hw[(q >> 4) * 24 + (q & 15)] = __float2half_rn(h1n);
        }
      }

      // ---- L1 gates ----
      if (do1) {
        const float r1 = sigmf(c_r + brz0);
        const float z1 = sigmf(c_z + brz1);
        const float n1 = tanh_fast(c_xn + bin + r1 * (c_hn + bhn));
        const float h2n = (1.0f - z1) * n1 + z1 * hprev2;
        hprev2 = h2n;
        if (c == 0) {
          __half* hw = reinterpret_cast<__half*>(&h2lds[nxt][0]);
          hw[(q >> 4) * 24 + (q & 15)] = __float2half_rn(h2n);
          houtb[(size_t)(p - 1) * ldh + q] = h2n;
        }
      }

      // ---- refill gx slot s with gx(p+2) (clamped; harmless at tail) ----
      {
        const int tp = (p + 2 < TT) ? (p + 2) : (TT - 1);
        const float* gxt = gxb + (size_t)tp * GG;
        #pragma unroll
        for (int rr = 0; rr < 3; ++rr) gxr[s][rr] = gxt[rows[rr]];
      }

      wg_barrier_lds();
    }
  }
}

// ---------------------------------------------------------------------------
// Tiled GEMM: C[M,N] = A[M,K] * Bw[N,K]^T + bias (optional ReLU).
// 128x128 tile, K staged in 32-chunks, 256 threads, 8x8/thread, float4 stores.
// ---------------------------------------------------------------------------
template <int K, bool RELU>
__global__ __launch_bounds__(256) void gemm_bias(
    const float* __restrict__ A, int lda,
    const float* __restrict__ Bw,       // [N, K] row-major
    const float* __restrict__ bias,     // [N]
    float* __restrict__ C, int ldc,
    int M, int N)
{
  __shared__ float As[128][33];
  __shared__ float Bs[128][33];

  const int tid = threadIdx.x;
  const int tx = tid & 15, ty = tid >> 4;
  const int row0 = blockIdx.x * 128, col0 = blockIdx.y * 128;

  float acc[8][8] = {};

  #pragma unroll
  for (int k0 = 0; k0 < K; k0 += 32) {
    const int kc = (K - k0 < 32) ? (K - k0) : 32;   // constant-folds per k0

    #pragma unroll
    for (int l = 0; l < 16; ++l) {
      const int idx = tid + l * 256;
      const int r = idx >> 5, cc = idx & 31;
      As[r][cc] = (cc < kc) ? A[(size_t)(row0 + r) * lda + k0 + cc] : 0.0f;
      const int n = col0 + r;
      Bs[r][cc] = (cc < kc && n < N) ? Bw[(size_t)n * K + k0 + cc] : 0.0f;
    }
    __syncthreads();

    #pragma unroll 4
    for (int kk = 0; kk < kc; ++kk) {
      float av[8], bv[8];
      #pragma unroll
      for (int i = 0; i < 8; ++i) av[i] = As[ty * 8 + i][kk];
      #pragma unroll
      for (int j = 0; j < 8; ++j) bv[j] = Bs[tx * 8 + j][kk];
      #pragma unroll
      for (int i = 0; i < 8; ++i)
        #pragma unroll
        for (int j = 0; j < 8; ++j)
          acc[i][j] = fmaf(av[i], bv[j], acc[i][j]);
    }
    __syncthreads();
  }

  #pragma unroll
  for (int i = 0; i < 8; ++i) {
    const int r = row0 + ty * 8 + i;
    #pragma unroll
    for (int jj = 0; jj < 2; ++jj) {
      const int cn = col0 + tx * 8 + jj * 4;
      if (cn < N) {   // N % 4 == 0 for all our shapes
        float4 v;
        v.x = acc[i][jj * 4 + 0] + bias[cn + 0];
        v.y = acc[i][jj * 4 + 1] + bias[cn + 1];
        v.z = acc[i][jj * 4 + 2] + bias[cn + 2];
        v.w = acc[i][jj * 4 + 3] + bias[cn + 3];
        if (RELU) {
          v.x = v.x > 0.f ? v.x : 0.f; v.y = v.y > 0.f ? v.y : 0.f;
          v.z = v.z > 0.f ? v.z : 0.f; v.w = v.w > 0.f ? v.w : 0.f;
        }
        *reinterpret_cast<float4*>(&C[(size_t)r * ldc + cn]) = v;
      }
    }
  }
}

// ---------------------------------------------------------------------------
extern "C" void kernel_launch(void* const* d_in, const int* in_sizes, int n_in,
                              void* d_out, int out_size, void* d_ws, size_t ws_size,
                              hipStream_t stream) {
  const float* x    = (const float*)d_in[0];
  const float* Wih0 = (const float*)d_in[1];
  const float* Whh0 = (const float*)d_in[2];
  const float* bih0 = (const float*)d_in[3];
  const float* bhh0 = (const float*)d_in[4];
  const float* Wih1 = (const float*)d_in[5];
  const float* Whh1 = (const float*)d_in[6];
  const float* bih1 = (const float*)d_in[7];
  const float* bhh1 = (const float*)d_in[8];
  const float* W1   = (const float*)d_in[9];
  const float* b1   = (const float*)d_in[10];
  const float* W2   = (const float*)d_in[11];
  const float* b2   = (const float*)d_in[12];
  float* out = (float*)d_out;

  const int M = BB * TT;  // 256000 rows
  float* gxbuf = (float*)d_ws;                       // M*384 floats
  float* h1buf = gxbuf + (size_t)M * GG;             // M*128 floats (head scratch)

  // 1) gx0 = x @ Wih0^T + bih0   (K=26 exact)
  gemm_bias<26, false><<<dim3(M / 128, 3), dim3(256), 0, stream>>>(
      x, 26, Wih0, bih0, gxbuf, GG, M, GG);

  // 2) fused 2-layer recurrence -> h2 in d_out rows (stride 136)
  gru2_fused<<<dim3(BB), dim3(1024), 0, stream>>>(
      gxbuf, Whh0, bhh0, Wih1, bih1, Whh1, bhh1, out, 136);

  // 3) hidden = relu(h2 @ W1^T + b1) -> h1buf
  gemm_bias<128, true><<<dim3(M / 128, 1), dim3(256), 0, stream>>>(
      out, 136, W1, b1, h1buf, HH, M, HH);

  // 4) out = hidden @ W2^T + b2 -> d_out
  gemm_bias<128, false><<<dim3(M / 128, 2), dim3(256), 0, stream>>>(
      h1buf, HH, W2, b2, out, 136, M, 136);
}

// Round 12
// 5952.729 us; speedup vs baseline: 1.2845x; 1.2845x over previous
//
#include <hip/hip_runtime.h>
#include <hip/hip_fp16.h>
#include <cstdint>

#define HH 128
#define GG 384   // 3H
#define TT 4000
#define BB 64

typedef uint32_t u32;

__device__ __forceinline__ float sigmf(float x) {
  return __fdividef(1.0f, 1.0f + __expf(-x));
}
__device__ __forceinline__ float tanh_fast(float x) {
  return __fdividef(2.0f, 1.0f + __expf(-2.0f * x)) - 1.0f;
}

template <int CTRL>
__device__ __forceinline__ float quad_add(float x) {
  int y = __builtin_amdgcn_mov_dpp(__float_as_int(x), CTRL, 0xF, 0xF, true);
  return x + __int_as_float(y);
}

// v_dot2_f32_f16: d = a.x*b.x + a.y*b.y + c  (fp16 mul exact into fp32 acc)
__device__ __forceinline__ float fdot2(u32 a, u32 b, float c) {
  float d;
  asm("v_dot2_f32_f16 %0, %1, %2, %3" : "=v"(d) : "v"(a), "v"(b), "v"(c));
  return d;
}

__device__ __forceinline__ u32 packh2(float a, float b) {
  __half2 h = __floats2half2_rn(a, b);
  union { __half2 h; u32 u; } cv;
  cv.h = h;
  return cv.u;
}

// LDS-only barrier: do NOT drain vmcnt (keeps global prefetch/stores in flight).
__device__ __forceinline__ void wg_barrier_lds() {
  asm volatile("s_waitcnt lgkmcnt(0)" ::: "memory");
  __builtin_amdgcn_s_barrier();
  asm volatile("" ::: "memory");
}

// ---------------------------------------------------------------------------
// FUSED 2-layer GRU (round-6 passing kernel, VERBATIM except one change:
// gx comes from LDS chunk-staging instead of per-step scattered global loads).
// 512 threads = 128 q x 4 k-chunks = 8 waves (2/SIMD).
//
// gx staging: rows pp..pp+3 are 1536 contiguous floats. Threads 0..383 load
// one float4 of the NEXT chunk at s==0 (HBM latency hidden under 2 steps)
// and ds_write it at s==2 into the t4-parity double buffer. Replaces
// 3 scattered global loads/thread/step (~98K VMEM ops/step chip-wide,
// x4 quad-redundant) with 3 broadcast ds_reads/step.
// ---------------------------------------------------------------------------
__global__ __launch_bounds__(512)
__attribute__((amdgpu_waves_per_eu(2, 2)))
void gru2_fused(
    const float* __restrict__ gx,     // [B,T,384] L0 input proj (incl bih0)
    const float* __restrict__ Whh0,   // [384,128]
    const float* __restrict__ bhh0,   // [384]
    const float* __restrict__ Wih1,   // [384,128]
    const float* __restrict__ bih1,   // [384]
    const float* __restrict__ Whh1,   // [384,128]
    const float* __restrict__ bhh1,   // [384]
    float* __restrict__ hout2,        // [B,T,ldh] L1 hidden states
    int ldh)
{
  __shared__ u32 h1lds[2][80];   // h as half2: 4 chunks x (16 used + 4 pad)
  __shared__ u32 h2lds[2][80];
  __shared__ float gxlds[2][4 * GG];   // 2 x 4 timesteps x 384 floats (12.3KB)

  const int tid = threadIdx.x;
  const int q = tid >> 2;   // 0..127
  const int c = tid & 3;    // k-chunk
  const int b = blockIdx.x;
  const int rows[3] = { q, q + 128, q + 256 };

  // weights -> packed half2 registers
  u32 w0[3][16], wi[3][16], wh[3][16];
  #pragma unroll
  for (int rr = 0; rr < 3; ++rr) {
    const float4* p0 = reinterpret_cast<const float4*>(Whh0 + (size_t)rows[rr] * HH + c * 32);
    const float4* p1 = reinterpret_cast<const float4*>(Wih1 + (size_t)rows[rr] * HH + c * 32);
    const float4* p2 = reinterpret_cast<const float4*>(Whh1 + (size_t)rows[rr] * HH + c * 32);
    #pragma unroll
    for (int p = 0; p < 8; ++p) {
      float4 v0 = p0[p], v1 = p1[p], v2 = p2[p];
      w0[rr][p * 2 + 0] = packh2(v0.x, v0.y); w0[rr][p * 2 + 1] = packh2(v0.z, v0.w);
      wi[rr][p * 2 + 0] = packh2(v1.x, v1.y); wi[rr][p * 2 + 1] = packh2(v1.z, v1.w);
      wh[rr][p * 2 + 0] = packh2(v2.x, v2.y); wh[rr][p * 2 + 1] = packh2(v2.z, v2.w);
    }
  }
  #pragma unroll
  for (int rr = 0; rr < 3; ++rr)
    #pragma unroll
    for (int kk = 0; kk < 16; ++kk) {
      asm volatile("" : "+v"(w0[rr][kk]));
      asm volatile("" : "+v"(wi[rr][kk]));
      asm volatile("" : "+v"(wh[rr][kk]));
    }

  float bh0[3];
  #pragma unroll
  for (int rr = 0; rr < 3; ++rr) bh0[rr] = bhh0[rows[rr]];
  const float brz0 = bih1[rows[0]] + bhh1[rows[0]];
  const float brz1 = bih1[rows[1]] + bhh1[rows[1]];
  const float bin  = bih1[rows[2]];
  const float bhn  = bhh1[rows[2]];

  for (int i = tid; i < 160; i += 512) {
    (&h1lds[0][0])[i] = 0u;
    (&h2lds[0][0])[i] = 0u;
  }

  const float* gxb = gx + (size_t)b * TT * GG;
  float* houtb = hout2 + (size_t)b * TT * ldh;

  float hprev1 = 0.0f, hprev2 = 0.0f;

  // prologue: stage chunk 0 (rows 0..3 = 1536 contiguous floats)
  if (tid < 384) {
    float4 v = *reinterpret_cast<const float4*>(gxb + tid * 4);
    *reinterpret_cast<float4*>(&gxlds[0][tid * 4]) = v;
  }
  __syncthreads();

  float4 stg;   // in-flight next-chunk quarter (threads 0..383)

  #pragma unroll 1
  for (int pp = 0; pp <= TT; pp += 4) {
    const int cb4 = (pp >> 2) & 1;   // gxlds buffer for this chunk
    #pragma unroll
    for (int s = 0; s < 4; ++s) {
      const int p = pp + s;
      const int cur = s & 1, nxt = cur ^ 1;   // pp even => p&1 == s&1
      const bool do0 = (p < TT);              // produce h1(p)
      const bool do1 = (p >= 1) && (p <= TT); // produce h2(p-1)

      // issue next gx chunk load early (consumed at s==2; clamped at tail)
      if (s == 0 && tid < 384) {
        int base = pp + 4;
        if (base > TT - 4) base = TT - 4;
        stg = *reinterpret_cast<const float4*>(gxb + (size_t)base * GG + tid * 4);
      }

      // ---- L1 recurrent dots (h2(p-2)) first: h2v dies early ----
      float cr = 0.f, cz = 0.f, chn = 0.f, dr = 0.f, dz = 0.f, dhn = 0.f;
      if (do1) {
        u32 h2v[16];
        const uint4* hp = reinterpret_cast<const uint4*>(&h2lds[cur][c * 20]);
        #pragma unroll
        for (int i = 0; i < 4; ++i) {
          uint4 v = hp[i];
          h2v[i * 4 + 0] = v.x; h2v[i * 4 + 1] = v.y;
          h2v[i * 4 + 2] = v.z; h2v[i * 4 + 3] = v.w;
        }
        #pragma unroll
        for (int k2 = 0; k2 < 16; k2 += 2) {
          cr  = fdot2(h2v[k2],     wh[0][k2],     cr);
          cz  = fdot2(h2v[k2],     wh[1][k2],     cz);
          chn = fdot2(h2v[k2],     wh[2][k2],     chn);
          dr  = fdot2(h2v[k2 + 1], wh[0][k2 + 1], dr);
          dz  = fdot2(h2v[k2 + 1], wh[1][k2 + 1], dz);
          dhn = fdot2(h2v[k2 + 1], wh[2][k2 + 1], dhn);
        }
      }

      // ---- shared read of h1(p-1) ----
      u32 h1v[16];
      {
        const uint4* hp = reinterpret_cast<const uint4*>(&h1lds[cur][c * 20]);
        #pragma unroll
        for (int i = 0; i < 4; ++i) {
          uint4 v = hp[i];
          h1v[i * 4 + 0] = v.x; h1v[i * 4 + 1] = v.y;
          h1v[i * 4 + 2] = v.z; h1v[i * 4 + 3] = v.w;
        }
      }

      // ---- L0 dots (Whh0 . h1(p-1)) ----
      float a0 = 0.f, a1 = 0.f, a2 = 0.f, e0 = 0.f, e1 = 0.f, e2 = 0.f;
      if (do0) {
        #pragma unroll
        for (int k2 = 0; k2 < 16; k2 += 2) {
          a0 = fdot2(h1v[k2],     w0[0][k2],     a0);
          a1 = fdot2(h1v[k2],     w0[1][k2],     a1);
          a2 = fdot2(h1v[k2],     w0[2][k2],     a2);
          e0 = fdot2(h1v[k2 + 1], w0[0][k2 + 1], e0);
          e1 = fdot2(h1v[k2 + 1], w0[1][k2 + 1], e1);
          e2 = fdot2(h1v[k2 + 1], w0[2][k2 + 1], e2);
        }
      }

      // ---- L1 input-projection dots (Wih1 . h1(p-1)) ----
      float cxn = 0.f, dxn = 0.f;
      if (do1) {
        #pragma unroll
        for (int k2 = 0; k2 < 16; k2 += 2) {
          cr  = fdot2(h1v[k2],     wi[0][k2],     cr);
          cz  = fdot2(h1v[k2],     wi[1][k2],     cz);
          cxn = fdot2(h1v[k2],     wi[2][k2],     cxn);
          dr  = fdot2(h1v[k2 + 1], wi[0][k2 + 1], dr);
          dz  = fdot2(h1v[k2 + 1], wi[1][k2 + 1], dz);
          dxn = fdot2(h1v[k2 + 1], wi[2][k2 + 1], dxn);
        }
      }

      // ---- L0 gates ----
      if (do0) {
        a0 += e0; a1 += e1; a2 += e2;
        a0 = quad_add<0xB1>(a0); a0 = quad_add<0x4E>(a0);
        a1 = quad_add<0xB1>(a1); a1 = quad_add<0x4E>(a1);
        a2 = quad_add<0xB1>(a2); a2 = quad_add<0x4E>(a2);
        const float g0 = gxlds[cb4][s * GG + q];
        const float g1 = gxlds[cb4][s * GG + q + 128];
        const float g2 = gxlds[cb4][s * GG + q + 256];
        const float r = sigmf(g0 + a0 + bh0[0]);
        const float z = sigmf(g1 + a1 + bh0[1]);
        const float n = tanh_fast(g2 + r * (a2 + bh0[2]));
        const float h1n = (1.0f - z) * n + z * hprev1;
        hprev1 = h1n;
        if (c == 0) {
          __half* hw = reinterpret_cast<__half*>(&h1lds[nxt][(q >> 5) * 20]);
          hw[q & 31] = __float2half_rn(h1n);
        }
      }

      // ---- L1 gates ----
      if (do1) {
        cr += dr; cz += dz; cxn += dxn; chn += dhn;
        cr  = quad_add<0xB1>(cr);  cr  = quad_add<0x4E>(cr);
        cz  = quad_add<0xB1>(cz);  cz  = quad_add<0x4E>(cz);
        cxn = quad_add<0xB1>(cxn); cxn = quad_add<0x4E>(cxn);
        chn = quad_add<0xB1>(chn); chn = quad_add<0x4E>(chn);
        const float r1 = sigmf(cr + brz0);
        const float z1 = sigmf(cz + brz1);
        const float n1 = tanh_fast(cxn + bin + r1 * (chn + bhn));
        const float h2n = (1.0f - z1) * n1 + z1 * hprev2;
        hprev2 = h2n;
        if (c == 0) {
          __half* hw = reinterpret_cast<__half*>(&h2lds[nxt][(q >> 5) * 20]);
          hw[q & 31] = __float2half_rn(h2n);
          houtb[(size_t)(p - 1) * ldh + q] = h2n;
        }
      }

      // write staged next chunk into the other gx buffer (visible after the
      // s==2 barrier; consumed starting next pp block)
      if (s == 2 && tid < 384) {
        *reinterpret_cast<float4*>(&gxlds[cb4 ^ 1][tid * 4]) = stg;
      }

      wg_barrier_lds();
    }
  }
}

// ---------------------------------------------------------------------------
// Tiled GEMM: C[M,N] = A[M,K] * Bw[N,K]^T + bias (optional ReLU).
// 128x128 tile, K staged in 32-chunks, 256 threads, 8x8/thread, float4 stores.
// (round-6 passing version, unchanged)
// ---------------------------------------------------------------------------
template <int K, bool RELU>
__global__ __launch_bounds__(256) void gemm_bias(
    const float* __restrict__ A, int lda,
    const float* __restrict__ Bw,       // [N, K] row-major
    const float* __restrict__ bias,     // [N]
    float* __restrict__ C, int ldc,
    int M, int N)
{
  __shared__ float As[128][33];
  __shared__ float Bs[128][33];

  const int tid = threadIdx.x;
  const int tx = tid & 15, ty = tid >> 4;
  const int row0 = blockIdx.x * 128, col0 = blockIdx.y * 128;

  float acc[8][8] = {};

  #pragma unroll
  for (int k0 = 0; k0 < K; k0 += 32) {
    const int kc = (K - k0 < 32) ? (K - k0) : 32;   // constant-folds per k0

    #pragma unroll
    for (int l = 0; l < 16; ++l) {
      const int idx = tid + l * 256;
      const int r = idx >> 5, cc = idx & 31;
      As[r][cc] = (cc < kc) ? A[(size_t)(row0 + r) * lda + k0 + cc] : 0.0f;
      const int n = col0 + r;
      Bs[r][cc] = (cc < kc && n < N) ? Bw[(size_t)n * K + k0 + cc] : 0.0f;
    }
    __syncthreads();

    #pragma unroll 4
    for (int kk = 0; kk < kc; ++kk) {
      float av[8], bv[8];
      #pragma unroll
      for (int i = 0; i < 8; ++i) av[i] = As[ty * 8 + i][kk];
      #pragma unroll
      for (int j = 0; j < 8; ++j) bv[j] = Bs[tx * 8 + j][kk];
      #pragma unroll
      for (int i = 0; i < 8; ++i)
        #pragma unroll
        for (int j = 0; j < 8; ++j)
          acc[i][j] = fmaf(av[i], bv[j], acc[i][j]);
    }
    __syncthreads();
  }

  #pragma unroll
  for (int i = 0; i < 8; ++i) {
    const int r = row0 + ty * 8 + i;
    #pragma unroll
    for (int jj = 0; jj < 2; ++jj) {
      const int cn = col0 + tx * 8 + jj * 4;
      if (cn < N) {   // N % 4 == 0 for all our shapes
        float4 v;
        v.x = acc[i][jj * 4 + 0] + bias[cn + 0];
        v.y = acc[i][jj * 4 + 1] + bias[cn + 1];
        v.z = acc[i][jj * 4 + 2] + bias[cn + 2];
        v.w = acc[i][jj * 4 + 3] + bias[cn + 3];
        if (RELU) {
          v.x = v.x > 0.f ? v.x : 0.f; v.y = v.y > 0.f ? v.y : 0.f;
          v.z = v.z > 0.f ? v.z : 0.f; v.w = v.w > 0.f ? v.w : 0.f;
        }
        *reinterpret_cast<float4*>(&C[(size_t)r * ldc + cn]) = v;
      }
    }
  }
}

// ---------------------------------------------------------------------------
extern "C" void kernel_launch(void* const* d_in, const int* in_sizes, int n_in,
                              void* d_out, int out_size, void* d_ws, size_t ws_size,
                              hipStream_t stream) {
  const float* x    = (const float*)d_in[0];
  const float* Wih0 = (const float*)d_in[1];
  const float* Whh0 = (const float*)d_in[2];
  const float* bih0 = (const float*)d_in[3];
  const float* bhh0 = (const float*)d_in[4];
  const float* Wih1 = (const float*)d_in[5];
  const float* Whh1 = (const float*)d_in[6];
  const float* bih1 = (const float*)d_in[7];
  const float* bhh1 = (const float*)d_in[8];
  const float* W1   = (const float*)d_in[9];
  const float* b1   = (const float*)d_in[10];
  const float* W2   = (const float*)d_in[11];
  const float* b2   = (const float*)d_in[12];
  float* out = (float*)d_out;

  const int M = BB * TT;  // 256000 rows
  float* gxbuf = (float*)d_ws;                       // M*384 floats
  float* h1buf = gxbuf + (size_t)M * GG;             // M*128 floats (head scratch)

  // 1) gx0 = x @ Wih0^T + bih0   (K=26 exact)
  gemm_bias<26, false><<<dim3(M / 128, 3), dim3(256), 0, stream>>>(
      x, 26, Wih0, bih0, gxbuf, GG, M, GG);

  // 2) fused 2-layer recurrence -> h2 in d_out rows (stride 136)
  gru2_fused<<<dim3(BB), dim3(512), 0, stream>>>(
      gxbuf, Whh0, bhh0, Wih1, bih1, Whh1, bhh1, out, 136);

  // 3) hidden = relu(h2 @ W1^T + b1) -> h1buf
  gemm_bias<128, true><<<dim3(M / 128, 1), dim3(256), 0, stream>>>(
      out, 136, W1, b1, h1buf, HH, M, HH);

  // 4) out = hidden @ W2^T + b2 -> d_out
  gemm_bias<128, false><<<dim3(M / 128, 2), dim3(256), 0, stream>>>(
      h1buf, HH, W2, b2, out, 136, M, 136);
}